// Round 9
// baseline (165.378 us; speedup 1.0000x reference)
//
#include <hip/hip_runtime.h>

#define SPK 1024
#define UTT 64
#define DIM 256
#define EPSV 1e-5f
#define NROW (SPK * UTT)
#define NSL 16           // partial slices: (col-group g)*4 + wave -- RACE KEY
#define LOG2E 1.44269504f

typedef __attribute__((ext_vector_type(4))) float f32x4;    // MFMA accumulator
typedef __attribute__((ext_vector_type(2))) long long2v;    // 16 B = 2 fp8 ktile frags

#define EXP2(x) __builtin_amdgcn_exp2f(x)     // bare v_exp_f32, no libm guards

// pack 4 floats -> 4 fp8 e4m3 bytes
__device__ __forceinline__ int pk_fp8(float a, float b, float c, float d) {
    int v = __builtin_amdgcn_cvt_pk_fp8_f32(a, b, 0, false);   // bytes 0,1
    return  __builtin_amdgcn_cvt_pk_fp8_f32(c, d, v, true);    // bytes 2,3
}

// MFMA-fragment byte order for a 256-byte fp8 row/column:
// unit (r,quad) (16 B) = k-bytes [2r*32+quad*8 .. +8] ++ [(2r+1)*32+quad*8 .. +8].
// fragIdx maps original int-group g (bytes g*4..+4) -> stored int index.
__device__ __forceinline__ int fragIdx(int g) {
    return ((g >> 4) * 4 + ((g & 7) >> 1)) * 4 + ((g >> 3) & 1) * 2 + (g & 1);
}

// K1: one block (256 thr) per speaker; x read ONCE, fully coalesced, kept in
// registers (xv[16] float4/thread). Pass A: col sums -> csum (LDS), ||csum||^2,
// cincl8 (fp8 x16, fragment order). Pass B (no re-read): per-row ||x||^2 and
// x.csum via per-thread 4-col partials + 6-level wave butterfly; quantize en8
// (fp8 x16, fragment order) and fp32 texcl.
// launch_bounds (256,2): 256-VGPR cap -- live-set ~140 VGPRs MUST NOT SPILL.
__global__ __launch_bounds__(256, 2)
void k_prep(const float* __restrict__ x,
            unsigned char* __restrict__ cincl8,
            unsigned char* __restrict__ en8,
            float* __restrict__ texcl,
            const float* __restrict__ wp, const float* __restrict__ bp) {
    __shared__ float4 sc4[256];
    __shared__ float4 csq[64];
    __shared__ float sccs;
    int s = blockIdx.x, tid = threadIdx.x;
    int dq = tid & 63, ug = tid >> 6;            // col-quad, row-group
    const float4* x4 = (const float4*)(x + (size_t)s * UTT * DIM);

    // pass A: coalesced load (1KB/wave-instr), col sums over 64 rows
    float4 xv[16];
    float4 p = {0.f, 0.f, 0.f, 0.f};
#pragma unroll
    for (int i = 0; i < 16; ++i) {
        float4 v = x4[(ug * 16 + i) * 64 + dq];
        xv[i] = v;
        p.x += v.x; p.y += v.y; p.z += v.z; p.w += v.w;
    }
    sc4[tid] = p;
    __syncthreads();
    if (tid < 64) {
        float4 a = sc4[dq], b2 = sc4[64 + dq], c = sc4[128 + dq], d = sc4[192 + dq];
        float4 cs = {a.x + b2.x + c.x + d.x, a.y + b2.y + c.y + d.y,
                     a.z + b2.z + c.z + d.z, a.w + b2.w + c.w + d.w};
        csq[dq] = cs;                            // csum stays in LDS (no global)
        float s2 = cs.x * cs.x + cs.y * cs.y + cs.z * cs.z + cs.w * cs.w;
#pragma unroll
        for (int o = 1; o < 64; o <<= 1) s2 += __shfl_xor(s2, o);
        // c_incl = csum/(||csum|| + U*eps), quantized x16 into e4m3
        float inv = 16.f / (sqrtf(s2) + UTT * EPSV);
        ((int*)cincl8)[s * 64 + fragIdx(dq)] =
            pk_fp8(cs.x * inv, cs.y * inv, cs.z * inv, cs.w * inv);
        if (tid == 0) sccs = s2;
    }
    __syncthreads();
    float scc = sccs;
    float4 cv = csq[dq];
    float w = wp[0], b = bp[0];

    // pass B: per-row partials over this thread's 4 cols, butterfly all-reduce
    float sxl[16], scl[16];
#pragma unroll
    for (int i = 0; i < 16; ++i) {
        float4 v = xv[i];
        sxl[i] = v.x * v.x + v.y * v.y + v.z * v.z + v.w * v.w;
        scl[i] = v.x * cv.x + v.y * cv.y + v.z * cv.z + v.w * cv.w;
    }
#pragma unroll
    for (int o = 1; o < 64; o <<= 1)
#pragma unroll
        for (int i = 0; i < 16; ++i) {
            sxl[i] += __shfl_xor(sxl[i], o);
            scl[i] += __shfl_xor(scl[i], o);
        }
    // quantize rows into en8 (stored int index = fragIdx(col-group))
    int fi = fragIdx(dq);
#pragma unroll
    for (int i = 0; i < 16; ++i) {
        float inv = 16.f / (sqrtf(sxl[i]) + EPSV);
        ((int*)(en8 + (size_t)(s * UTT + ug * 16 + i) * DIM))[fi] =
            pk_fp8(xv[i].x * inv, xv[i].y * inv, xv[i].z * inv, xv[i].w * inv);
    }
    if (dq == 0) {
        // sim_excl = x.(csum-x) / ((||x||+eps)(||csum-x||+63eps))  (fp32 exact)
#pragma unroll
        for (int i = 0; i < 16; ++i) {
            float nx = sqrtf(sxl[i]);
            float num = scl[i] - sxl[i];
            float e2 = fmaxf(scc - 2.f * scl[i] + sxl[i], 0.f);
            float sim = num / ((nx + EPSV) * (sqrtf(e2) + (UTT - 1) * EPSV));
            texcl[s * UTT + ug * 16 + i] = fmaf(sim, w, b);
        }
    }
}

// K2: round-6 structure (best measured, verified correct) + XCD-local A
// reuse. Block = (speaker-chunk c of 4 speakers) x (col-group g of 256
// cols); wave = 64 fixed cols. BID SWIZZLE: b = (c&7) + 8*g + 32*(c>>3)
// puts ALL 4 g-blocks of chunk c on the SAME XCD (b%8 const) -> each
// speaker's en8 (16 KB) crosses L3 once and is served to the other
// consumers from the 4 MB per-XCD L2 (round-6's FETCH=2x-en8 showed the
// default round-robin placement forced cross-XCD L3/HBM re-fetches --
// the ~300 MB L3 traffic that every 45-55us variant shared).
// 16 (sp,mt) tiles flattened into one fully-unrolled stream with 1-tile
// af prefetch (parity-selected static double buffer, rule-#20 safe).
// Epilogue: unconditional exp-accumulate, rare wave-uniform diag undo,
// 16-lane shfl reduce, slice (g*4+wave) store (verified race key).
// Zero LDS, zero barriers.
__global__ __launch_bounds__(256, 4)
void k_main(const unsigned char* __restrict__ en8,
            const unsigned char* __restrict__ cincl8,
            float* __restrict__ partial,
            const float* __restrict__ wp, const float* __restrict__ bp) {
    int tid = threadIdx.x, wave = tid >> 6, lane = tid & 63;
    int quad = lane >> 4, lx = lane & 15;
    int bid = blockIdx.x;
    int xcd = bid & 7, t = bid >> 3;
    int g = t & 3;                               // col-group (256 cols)
    int c = (t >> 2) * 8 + xcd;                  // speaker chunk (4 speakers)
    float w = wp[0], b = bp[0];
    float M  = fabsf(w) * 1.0625f + b;           // >= any logit (|sim| <= ~1)
    float wl = w * (LOG2E / 256.f);              // undo x16*x16 quant scale
    float bl = (b - M) * LOG2E;                  // exp(v-M) = exp2(acc*wl + bl)

    int col0 = g * 256 + wave * 64;              // wave's 64 cols
    long2v bf[4][4];                             // bf[nt][r]: col col0+nt*16+lx
#pragma unroll
    for (int nt = 0; nt < 4; ++nt)
#pragma unroll
        for (int r = 0; r < 4; ++r)
            bf[nt][r] = *(const long2v*)(cincl8 +
                (size_t)(col0 + nt * 16 + lx) * DIM + (r * 4 + quad) * 16);

    float* pb = partial + (size_t)(g * 4 + wave) * NROW;

#define LOADA(dst, uv) {                                                        \
    const unsigned char* ab_ = en8 +                                            \
        (size_t)(c * 4 + ((uv) >> 2)) * UTT * DIM;                              \
    _Pragma("unroll")                                                           \
    for (int r = 0; r < 4; ++r)                                                 \
        dst[r] = *(const long2v*)(ab_ + (((uv) & 3) * 16 + lx) * DIM            \
                                       + (r * 4 + quad) * 16);                  \
}

#define TILE(afb, uv) {                                                         \
    int s_ = c * 4 + ((uv) >> 2), mt_ = (uv) & 3;                               \
    bool dgw = ((s_ >> 8) == g) && (((s_ >> 6) & 3) == wave);                   \
    int nt_d = (s_ >> 4) & 3, lx_d = s_ & 15;                                   \
    f32x4 acc[4] = {{0.f,0.f,0.f,0.f},{0.f,0.f,0.f,0.f},                        \
                    {0.f,0.f,0.f,0.f},{0.f,0.f,0.f,0.f}};                       \
    _Pragma("unroll")                                                           \
    for (int r = 0; r < 4; ++r) {                                               \
        _Pragma("unroll")                                                       \
        for (int nt = 0; nt < 4; ++nt)                                          \
            acc[nt] = __builtin_amdgcn_mfma_f32_16x16x32_fp8_fp8(afb[r].x, bf[nt][r].x, acc[nt], 0, 0, 0); \
        _Pragma("unroll")                                                       \
        for (int nt = 0; nt < 4; ++nt)                                          \
            acc[nt] = __builtin_amdgcn_mfma_f32_16x16x32_fp8_fp8(afb[r].y, bf[nt][r].y, acc[nt], 0, 0, 0); \
    }                                                                           \
    float ps[4] = {0.f, 0.f, 0.f, 0.f};                                         \
    _Pragma("unroll")                                                           \
    for (int nt = 0; nt < 4; ++nt)                                              \
        _Pragma("unroll")                                                       \
        for (int i = 0; i < 4; ++i)                                             \
            ps[i] += EXP2(fmaf(acc[nt][i], wl, bl));                            \
    if (dgw) {                        /* rare, wave-uniform diag undo */        \
        _Pragma("unroll")                                                       \
        for (int nt = 0; nt < 4; ++nt)                                          \
            if (nt == nt_d)           /* static acc index (rule #20) */         \
                _Pragma("unroll")                                               \
                for (int i = 0; i < 4; ++i) {                                   \
                    float e = EXP2(fmaf(acc[nt][i], wl, bl));                   \
                    if (lx == lx_d) ps[i] -= e;                                 \
                }                                                               \
    }                                                                           \
    _Pragma("unroll")                                                           \
    for (int o = 1; o < 16; o <<= 1)  /* reduce over the 16 col-lanes */        \
        _Pragma("unroll")                                                       \
        for (int i = 0; i < 4; ++i) ps[i] += __shfl_xor(ps[i], o);              \
    if (lx == 0)                                                                \
        *(float4*)(pb + (size_t)s_ * UTT + mt_ * 16 + quad * 4) =               \
            (float4){ps[0], ps[1], ps[2], ps[3]};                               \
}

    // 16 (sp,mt) tiles, fully unrolled, 1-tile-ahead A prefetch.
    long2v afA[4], afB[4];
    LOADA(afA, 0);
#pragma unroll
    for (int u = 0; u < 16; ++u) {               // u compile-time after unroll
        if (u + 1 < 16) {
            if (u & 1) { LOADA(afA, u + 1); }    // static parity select
            else       { LOADA(afB, u + 1); }
        }
        if (u & 1) { TILE(afB, u); }
        else       { TILE(afA, u); }
    }
#undef LOADA
#undef TILE
}

// K3: combine the 16 (col-group, wave) partials per row, logsumexp, mean.
__global__ __launch_bounds__(256)
void k_final(const float* __restrict__ partial, const float* __restrict__ texcl,
             const float* __restrict__ wp, const float* __restrict__ bp,
             float* __restrict__ out) {
    int row = blockIdx.x * 256 + threadIdx.x;
    float w = wp[0], b = bp[0];
    float M = fabsf(w) * 1.0625f + b;
    float t = 0.f;
#pragma unroll
    for (int sl = 0; sl < NSL; ++sl) t += partial[(size_t)sl * NROW + row];
    float tex = texcl[row];
    float c = (M + __logf(t + EXP2((tex - M) * LOG2E))) - tex;   // lse - target
#pragma unroll
    for (int o = 1; o < 64; o <<= 1) c += __shfl_xor(c, o);
    __shared__ float red[4];
    if ((threadIdx.x & 63) == 0) red[threadIdx.x >> 6] = c;
    __syncthreads();
    if (threadIdx.x == 0)
        atomicAdd(out, (red[0] + red[1] + red[2] + red[3]) * (1.f / NROW));
}

extern "C" void kernel_launch(void* const* d_in, const int* in_sizes, int n_in,
                              void* d_out, int out_size, void* d_ws, size_t ws_size,
                              hipStream_t stream) {
    const float* x  = (const float*)d_in[0];
    const float* wp = (const float*)d_in[1];
    const float* bp = (const float*)d_in[2];
    char* ws = (char*)d_ws;
    unsigned char* cincl8 = (unsigned char*)ws;                     // @0,    256 KB
    float* texcl          = (float*)(ws + (1u << 19));              // @512K, 256 KB
    float* partial        = (float*)(ws + (1u << 20));              // @1M,   4 MB
    unsigned char* en8    = (unsigned char*)(ws + (8u << 20));      // @8M,   16 MB
    float* out = (float*)d_out;

    hipMemsetAsync(d_out, 0, sizeof(float), stream);
    k_prep <<<SPK, 256, 0, stream>>>(x, cincl8, en8, texcl, wp, bp);
    k_main <<<4 * (SPK / 4), 256, 0, stream>>>(en8, cincl8, partial, wp, bp);
    k_final<<<NROW / 256, 256, 0, stream>>>(partial, texcl, wp, bp, out);
}

// Round 10
// 144.461 us; speedup vs baseline: 1.1448x; 1.1448x over previous
//
#include <hip/hip_runtime.h>

#define SPK 1024
#define UTT 64
#define DIM 256
#define EPSV 1e-5f
#define NROW (SPK * UTT)
#define NSL 8            // column slices (128 cols each)
#define LOG2E 1.44269504f

typedef __attribute__((ext_vector_type(4))) float f32x4;    // MFMA accumulator
typedef __attribute__((ext_vector_type(2))) long long2v;    // 16 B = 2 fp8 ktile frags

#define EXP2(x) __builtin_amdgcn_exp2f(x)     // bare v_exp_f32, no libm guards

// pack 4 floats -> 4 fp8 e4m3 bytes
__device__ __forceinline__ int pk_fp8(float a, float b, float c, float d) {
    int v = __builtin_amdgcn_cvt_pk_fp8_f32(a, b, 0, false);   // bytes 0,1
    return  __builtin_amdgcn_cvt_pk_fp8_f32(c, d, v, true);    // bytes 2,3
}

// MFMA-fragment byte order for a 256-byte fp8 row/column:
// unit (r,quad) (16 B) = k-bytes [2r*32+quad*8 .. +8] ++ [(2r+1)*32+quad*8 .. +8].
// fragIdx maps original int-group g (bytes g*4..+4) -> stored int index.
__device__ __forceinline__ int fragIdx(int g) {
    return ((g >> 4) * 4 + ((g & 7) >> 1)) * 4 + ((g >> 3) & 1) * 2 + (g & 1);
}

// K1: one block (256 thr) per speaker; x read ONCE, fully coalesced, kept in
// registers (xv[16] float4/thread). Pass A: col sums -> csum (LDS), ||csum||^2,
// cincl8 (fp8 x16, fragment order). Pass B (no re-read): per-row ||x||^2 and
// x.csum via per-thread 4-col partials + 6-level wave butterfly.
// en8 STORE PATH (round-10 fix): the old path scattered 4-B ints at 256-B
// stride (64 cache lines per wave-store; ~half of k_prep's time). Now packed
// ints go to a padded LDS transpose buffer tr[row][fragIdx] (2 lanes/bank =
// free), one barrier, then COALESCED int4 stores (4 KB per wave-instr).
__global__ __launch_bounds__(256, 2)
void k_prep(const float* __restrict__ x,
            unsigned char* __restrict__ cincl8,
            unsigned char* __restrict__ en8,
            float* __restrict__ texcl,
            const float* __restrict__ wp, const float* __restrict__ bp) {
    __shared__ float4 sc4[256];
    __shared__ float4 csq[64];
    __shared__ float sccs;
    __shared__ int tr[64 * 68];                  // 17 KB: 64 rows, pad 68 ints
    int s = blockIdx.x, tid = threadIdx.x;
    int dq = tid & 63, ug = tid >> 6;            // col-quad, row-group
    const float4* x4 = (const float4*)(x + (size_t)s * UTT * DIM);

    // pass A: coalesced load (1KB/wave-instr), col sums over 64 rows
    float4 xv[16];
    float4 p = {0.f, 0.f, 0.f, 0.f};
#pragma unroll
    for (int i = 0; i < 16; ++i) {
        float4 v = x4[(ug * 16 + i) * 64 + dq];
        xv[i] = v;
        p.x += v.x; p.y += v.y; p.z += v.z; p.w += v.w;
    }
    sc4[tid] = p;
    __syncthreads();
    if (tid < 64) {
        float4 a = sc4[dq], b2 = sc4[64 + dq], c = sc4[128 + dq], d = sc4[192 + dq];
        float4 cs = {a.x + b2.x + c.x + d.x, a.y + b2.y + c.y + d.y,
                     a.z + b2.z + c.z + d.z, a.w + b2.w + c.w + d.w};
        csq[dq] = cs;                            // csum stays in LDS (no global)
        float s2 = cs.x * cs.x + cs.y * cs.y + cs.z * cs.z + cs.w * cs.w;
#pragma unroll
        for (int o = 1; o < 64; o <<= 1) s2 += __shfl_xor(s2, o);
        // c_incl = csum/(||csum|| + U*eps), quantized x16 into e4m3
        float inv = 16.f / (sqrtf(s2) + UTT * EPSV);
        ((int*)cincl8)[s * 64 + fragIdx(dq)] =
            pk_fp8(cs.x * inv, cs.y * inv, cs.z * inv, cs.w * inv);
        if (tid == 0) sccs = s2;
    }
    __syncthreads();
    float scc = sccs;
    float4 cv = csq[dq];
    float w = wp[0], b = bp[0];

    // pass B: per-row partials over this thread's 4 cols, butterfly all-reduce
    float sxl[16], scl[16];
#pragma unroll
    for (int i = 0; i < 16; ++i) {
        float4 v = xv[i];
        sxl[i] = v.x * v.x + v.y * v.y + v.z * v.z + v.w * v.w;
        scl[i] = v.x * cv.x + v.y * cv.y + v.z * cv.z + v.w * cv.w;
    }
#pragma unroll
    for (int o = 1; o < 64; o <<= 1)
#pragma unroll
        for (int i = 0; i < 16; ++i) {
            sxl[i] += __shfl_xor(sxl[i], o);
            scl[i] += __shfl_xor(scl[i], o);
        }
    // quantize rows into the LDS transpose buffer (same (row, int) pairs as
    // the old direct store: int index = fragIdx(col-group dq))
    int fi = fragIdx(dq);
#pragma unroll
    for (int i = 0; i < 16; ++i) {
        float inv = 16.f / (sqrtf(sxl[i]) + EPSV);
        tr[(ug * 16 + i) * 68 + fi] =
            pk_fp8(xv[i].x * inv, xv[i].y * inv, xv[i].z * inv, xv[i].w * inv);
    }
    if (dq == 0) {
        // sim_excl = x.(csum-x) / ((||x||+eps)(||csum-x||+63eps))  (fp32 exact)
#pragma unroll
        for (int i = 0; i < 16; ++i) {
            float nx = sqrtf(sxl[i]);
            float num = scl[i] - sxl[i];
            float e2 = fmaxf(scc - 2.f * scl[i] + sxl[i], 0.f);
            float sim = num / ((nx + EPSV) * (sqrtf(e2) + (UTT - 1) * EPSV));
            texcl[s * UTT + ug * 16 + i] = fmaf(sim, w, b);
        }
    }
    __syncthreads();                             // tr complete
    // coalesced en8 store: thread t owns (row = t>>2, chunk ch = t&3);
    // 4 x int4 per thread; wave covers 4 KB contiguous per iteration.
    int row = tid >> 2, ch = tid & 3;
    unsigned char* gout = en8 + (size_t)(s * UTT + row) * DIM + ch * 64;
    const int* lsrc = &tr[row * 68 + ch * 16];
#pragma unroll
    for (int k = 0; k < 4; ++k)
        *(int4*)(gout + k * 16) = *(const int4*)(lsrc + k * 4);
}

// K2 (round-0 verbatim, proven): fp8 matmul. Block = 4 speakers x one
// 128-col slice. Both operands in MFMA-fragment order: staging = per-lane
// 16 B global_load_lds into region+lane*16; hot loop = ds_read_b128 at
// lane*16 (verified ZERO-conflict pattern) giving 2 ktiles per read;
// A-frags = global b128. One barrier per block; XCD swizzle keeps a
// group's en8 on one XCD.
__global__ __launch_bounds__(256, 3)
void k_main(const unsigned char* __restrict__ en8,
            const unsigned char* __restrict__ cincl8,
            float* __restrict__ partial,
            const float* __restrict__ wp, const float* __restrict__ bp) {
    __shared__ unsigned char Bs[32 * 1024];      // 32 regions (nt,r) x 1 KB
    int tid = threadIdx.x, wave = tid >> 6, lane = tid & 63;
    int quad = lane >> 4, lx = lane & 15;
    int bid = blockIdx.x;
    int xcd = bid & 7, j = bid >> 3;             // j in [0,256)
    int cs = j & 7;                              // column slice (0..7)
    int sg = xcd + 8 * (j >> 3);                 // speaker group (0..255)
    int sw = sg * 4 + wave;                      // this wave's speaker
    float w = wp[0], b = bp[0];
    float M  = fabsf(w) * 1.0625f + b;           // >= any logit (|sim| <= ~1)
    float wl = w * (LOG2E / 256.f);              // undo x16*x16 quant scale
    float bl = (b - M) * LOG2E;                  // exp(v-M) = exp2(acc*wl + bl)

    // stage B: region (nt,r) = 1 KB at (nt*4+r)*1024; lane ℓ supplies col
    // cs*128+nt*16+(ℓ&15), unit (r, ℓ>>4) -> LDS region + ℓ*16 (HW rule).
#pragma unroll
    for (int nti = 0; nti < 2; ++nti) {
        int nt = wave * 2 + nti;
#pragma unroll
        for (int r = 0; r < 4; ++r) {
            const unsigned char* g = cincl8 +
                (size_t)(cs * 128 + nt * 16 + lx) * DIM + (r * 4 + quad) * 16;
            __builtin_amdgcn_global_load_lds(
                (const __attribute__((address_space(1))) void*)g,
                (__attribute__((address_space(3))) void*)(Bs + (nt * 4 + r) * 1024),
                16, 0, 0);
        }
    }

    // A fragments (fragment-order rows): af2[mt][r] = ktiles (2r, 2r+1)
    const unsigned char* abase = en8 + (size_t)sw * UTT * DIM;
    long2v af2[4][4];
#pragma unroll
    for (int mt = 0; mt < 4; ++mt)
#pragma unroll
        for (int r = 0; r < 4; ++r)
            af2[mt][r] = *(const long2v*)(abase + (mt * 16 + lx) * DIM + (r * 4 + quad) * 16);

    float l[16];
#pragma unroll
    for (int i = 0; i < 16; ++i) l[i] = 0.f;

    __syncthreads();                             // staging complete (only barrier)

    int dnt = (sw >> 4) - cs * 8;                // diag ntile if in [0,8)
    int dlx = sw & 15;

    for (int nt = 0; nt < 8; ++nt) {
        long2v bf2[4];
#pragma unroll
        for (int r = 0; r < 4; ++r)
            bf2[r] = *(const long2v*)(Bs + (nt * 4 + r) * 1024 + lane * 16);
        f32x4 aA[4] = {{0.f,0.f,0.f,0.f},{0.f,0.f,0.f,0.f},
                       {0.f,0.f,0.f,0.f},{0.f,0.f,0.f,0.f}};
        f32x4 aB[4] = {{0.f,0.f,0.f,0.f},{0.f,0.f,0.f,0.f},
                       {0.f,0.f,0.f,0.f},{0.f,0.f,0.f,0.f}};
#pragma unroll
        for (int r = 0; r < 2; ++r) {            // 8 interleaved MFMA chains
#pragma unroll
            for (int mt = 0; mt < 4; ++mt) {
                aA[mt] = __builtin_amdgcn_mfma_f32_16x16x32_fp8_fp8(af2[mt][r].x,   bf2[r].x,   aA[mt], 0, 0, 0);
                aB[mt] = __builtin_amdgcn_mfma_f32_16x16x32_fp8_fp8(af2[mt][r+2].x, bf2[r+2].x, aB[mt], 0, 0, 0);
            }
#pragma unroll
            for (int mt = 0; mt < 4; ++mt) {
                aA[mt] = __builtin_amdgcn_mfma_f32_16x16x32_fp8_fp8(af2[mt][r].y,   bf2[r].y,   aA[mt], 0, 0, 0);
                aB[mt] = __builtin_amdgcn_mfma_f32_16x16x32_fp8_fp8(af2[mt][r+2].y, bf2[r+2].y, aB[mt], 0, 0, 0);
            }
        }
#pragma unroll
        for (int mt = 0; mt < 4; ++mt)
#pragma unroll
            for (int r = 0; r < 4; ++r)
                l[mt * 4 + r] += EXP2(fmaf(aA[mt][r] + aB[mt][r], wl, bl));
        if (nt == dnt) {                          // wave-uniform: undo diag col
#pragma unroll
            for (int mt = 0; mt < 4; ++mt)
#pragma unroll
                for (int r = 0; r < 4; ++r) {
                    float e = EXP2(fmaf(aA[mt][r] + aB[mt][r], wl, bl));
                    if (lx == dlx) l[mt * 4 + r] -= e;
                }
        }
    }

    // reduce over the 16 col-lanes; rows live at (quad, mt, r)
#pragma unroll
    for (int o = 1; o < 16; o <<= 1)
#pragma unroll
        for (int i = 0; i < 16; ++i) l[i] += __shfl_xor(l[i], o);
    if (lx == 0)
#pragma unroll
        for (int mt = 0; mt < 4; ++mt)
#pragma unroll
            for (int r = 0; r < 4; ++r)
                partial[(size_t)cs * NROW + (size_t)sw * UTT + mt * 16 + quad * 4 + r]
                    = l[mt * 4 + r];
}

// K3: combine the 8 slice partials per row, logsumexp, mean-reduce.
__global__ __launch_bounds__(256)
void k_final(const float* __restrict__ partial, const float* __restrict__ texcl,
             const float* __restrict__ wp, const float* __restrict__ bp,
             float* __restrict__ out) {
    int row = blockIdx.x * 256 + threadIdx.x;
    float w = wp[0], b = bp[0];
    float M = fabsf(w) * 1.0625f + b;
    float t = 0.f;
#pragma unroll
    for (int sl = 0; sl < NSL; ++sl) t += partial[(size_t)sl * NROW + row];
    float tex = texcl[row];
    float c = (M + __logf(t + EXP2((tex - M) * LOG2E))) - tex;   // lse - target
#pragma unroll
    for (int o = 1; o < 64; o <<= 1) c += __shfl_xor(c, o);
    __shared__ float red[4];
    if ((threadIdx.x & 63) == 0) red[threadIdx.x >> 6] = c;
    __syncthreads();
    if (threadIdx.x == 0)
        atomicAdd(out, (red[0] + red[1] + red[2] + red[3]) * (1.f / NROW));
}

extern "C" void kernel_launch(void* const* d_in, const int* in_sizes, int n_in,
                              void* d_out, int out_size, void* d_ws, size_t ws_size,
                              hipStream_t stream) {
    const float* x  = (const float*)d_in[0];
    const float* wp = (const float*)d_in[1];
    const float* bp = (const float*)d_in[2];
    char* ws = (char*)d_ws;
    unsigned char* cincl8 = (unsigned char*)ws;                     // @0,    256 KB
    float* texcl          = (float*)(ws + (1u << 19));              // @512K, 256 KB
    float* partial        = (float*)(ws + (1u << 20));              // @1M,   2 MB
    unsigned char* en8    = (unsigned char*)(ws + (4u << 20));      // @4M,   16 MB
    float* out = (float*)d_out;

    hipMemsetAsync(d_out, 0, sizeof(float), stream);
    k_prep <<<SPK, 256, 0, stream>>>(x, cincl8, en8, texcl, wp, bp);
    k_main <<<(SPK / 4) * NSL, 256, 0, stream>>>(en8, cincl8, partial, wp, bp);
    k_final<<<NROW / 256, 256, 0, stream>>>(partial, texcl, wp, bp, out);
}